// Round 4
// baseline (789.659 us; speedup 1.0000x reference)
//
#include <hip/hip_runtime.h>
#include <hip/hip_bf16.h>
#include <stdint.h>

#define N_NODES 4096
#define N_EDGES 8192
#define IN_V    512
#define OUT_V   512
#define IN_E    128

typedef __bf16 bf16;
typedef __bf16 bf16x8 __attribute__((ext_vector_type(8)));
typedef __bf16 bf16x4 __attribute__((ext_vector_type(4)));
typedef float  f32x4  __attribute__((ext_vector_type(4)));

// Async global->LDS, 16B per lane. LDS dest is wave-uniform base + lane*16.
__device__ __forceinline__ void g2l16(const void* g, void* l) {
    __builtin_amdgcn_global_load_lds(
        (const __attribute__((address_space(1))) void*)g,
        (__attribute__((address_space(3))) void*)l,
        16, 0, 0);
}

// -------- e_scale = H_e @ p^T : one wave per edge row (K=128) --------
__global__ void escale_k(const float* __restrict__ He, const float* __restrict__ p,
                         float* __restrict__ es) {
    const int row  = blockIdx.x * 4 + (threadIdx.x >> 6);
    const int lane = threadIdx.x & 63;
    const float* r = He + (size_t)row * IN_E;
    float v = r[lane] * p[lane] + r[lane + 64] * p[lane + 64];
#pragma unroll
    for (int off = 32; off > 0; off >>= 1) v += __shfl_down(v, off);
    if (lane == 0) es[row] = v;
}

// -------- T (f32 [N][E]) -> Tb = bf16(T), Ts = bf16(T * e_scale[col]) --------
__global__ void conv_T(const float* __restrict__ T, const float* __restrict__ es,
                       bf16* __restrict__ Ts, bf16* __restrict__ Tb) {
    const size_t i4 = (size_t)blockIdx.x * 256 + threadIdx.x;  // float4 index
    const f32x4 t = ((const f32x4*)T)[i4];
    const int  c4 = (int)(i4 & (N_EDGES / 4 - 1));
    const f32x4 s = ((const f32x4*)es)[c4];
    bf16x4 tb, ts;
#pragma unroll
    for (int j = 0; j < 4; j++) { tb[j] = (bf16)t[j]; ts[j] = (bf16)(t[j] * s[j]); }
    ((bf16x4*)Tb)[i4] = tb;
    ((bf16x4*)Ts)[i4] = ts;
}

// -------- generic f32 -> bf16 (vectorized x4) --------
__global__ void conv_bf16(const float* __restrict__ in, bf16* __restrict__ o) {
    const size_t i4 = (size_t)blockIdx.x * 256 + threadIdx.x;
    const f32x4 t = ((const f32x4*)in)[i4];
    bf16x4 v;
#pragma unroll
    for (int j = 0; j < 4; j++) v[j] = (bf16)t[j];
    ((bf16x4*)o)[i4] = v;
}

// -------- weight [512][512] f32 -> Wt bf16 with Wt[j][k] = W[k][j] --------
__global__ void transW(const float* __restrict__ W, bf16* __restrict__ Wt) {
    const int idx = blockIdx.x * 256 + threadIdx.x;  // output index j*512+k
    const int j = idx >> 9, k = idx & 511;
    Wt[idx] = (bf16)W[k * OUT_V + j];
}

// -------- finalize: out[i][j] = bias[j] + 0.5 * sum_z partial[z][i][j] -------
__global__ void finalize_k(const float* __restrict__ part, const float* __restrict__ bias,
                           float* __restrict__ out) {
    const size_t i4  = (size_t)blockIdx.x * 256 + threadIdx.x;
    const size_t npp = (size_t)N_NODES * OUT_V / 4;  // one partial in f32x4 units
    const f32x4 b  = ((const f32x4*)bias)[i4 & (OUT_V / 4 - 1)];
    const f32x4 s0 = ((const f32x4*)part)[i4];
    const f32x4 s1 = ((const f32x4*)part)[i4 + npp];
    const f32x4 s2 = ((const f32x4*)part)[i4 + 2 * npp];
    const f32x4 s3 = ((const f32x4*)part)[i4 + 3 * npp];
    f32x4 r;
#pragma unroll
    for (int j = 0; j < 4; j++) r[j] = b[j] + 0.5f * ((s0[j] + s1[j]) + (s2[j] + s3[j]));
    ((f32x4*)out)[i4] = r;
}

// -------- BT-GEMM: C[i][j] = sum_k A[i,k]*B[j,k]  (A: M x K, B: N x K, bf16)
// NEW shape this round: 128x64 block tile, BK=32, 128 threads = 2 waves,
// each wave owns a 64x64 sub-tile (4x4 16x16x32 MFMA fragments — identical
// per-wave structure to the verified round-1 kernel). LDS 24 KB -> 6-block
// residency; the EPI=1 triangular grid grows 528 -> 1056 blocks = 4.1
// independent blocks/CU (same 8.25 waves/CU, but 4 independent k-pipelines
// instead of 2 -> a stage drain in one block is covered by 3 others).
// Sync structure = the PROVEN 2-phase double-buffer with __syncthreads
// (the round-2/3 counted-vmcnt ring regressed; reverted).
// Requires KS % 64 == 0 (call sites: 512 / 8192 / 1024).
// EPI 0: store bf16 C
// EPI 1: SYMMETRIC A2 epilogue (M1 = M1^T), triangular grid by <= 2*bx+1
//        with XCD-chunked swizzle (1056 = 8*132). Per-ELEMENT rule:
//        direct write (c+1)*adj iff gm>gn, 2*adj iff gm==gn; mirror write
//        to (gn,gm) iff gm>gn. Every element of A2 written exactly once.
// EPI 3: store f32 C into partial[blockIdx.z] (split-K, no atomics)
template <int EPI>
__global__ __launch_bounds__(128, 3) void gemm_bt(
    const bf16* __restrict__ A, const bf16* __restrict__ B,
    const float* __restrict__ aux, void* __restrict__ out,
    int M, int N, int K, int KS) {
    __shared__ __align__(16) bf16 As[2][128 * 32];  // 16 KB
    __shared__ __align__(16) bf16 Bs[2][64 * 32];   // 8 KB
    const int tid  = threadIdx.x;
    const int wave = tid >> 6;   // 0..1
    const int lane = tid & 63;

    int bx, by;
    if constexpr (EPI == 1) {
        // XCD-chunked swizzle: 1056 blocks = 8 XCDs x 132 contiguous indices.
        int idx = (int)blockIdx.x;
        idx = (idx & 7) * 132 + (idx >> 3);
        // triangular decode: cumulative blocks before bx is bx*(bx+1);
        // by in [0, 2*bx+2)
        bx = (int)((sqrtf(4.0f * (float)idx + 1.0f) - 1.0f) * 0.5f);
        while ((bx + 1) * (bx + 2) <= idx) bx++;
        while (bx * (bx + 1) > idx) bx--;
        by = idx - bx * (bx + 1);
    } else {
        bx = blockIdx.x;
        by = blockIdx.y;
    }
    const int bm0 = bx * 128;   // A-rows (output rows)
    const int bn0 = by * 64;    // B-rows (output cols)
    const int wr  = wave * 64;  // wave's output-row offset in tile

    // staging: A tile 128 rows x 64B (wave stages its own 64 rows, 4 issues),
    // B tile 64 rows x 64B (wave stages 32 rows, 2 issues). 16 rows/issue.
    const int sr = lane >> 2;           // 0..15
    const int sb = (lane & 3) * 16;     // byte offset within 64B row
    const char* Ag = (const char*)A + (size_t)(bm0 + wr + sr) * K * 2 + sb;
    const char* Bg = (const char*)B + (size_t)(bn0 + wave * 32 + sr) * K * 2 + sb;
    const size_t rs16 = (size_t)16 * K * 2;  // 16-row stride in bytes

    f32x4 acc[4][4];
#pragma unroll
    for (int i = 0; i < 4; i++)
#pragma unroll
        for (int j = 0; j < 4; j++) acc[i][j] = f32x4{0.f, 0.f, 0.f, 0.f};

    // LDS read offsets (elements): A frag row wr + (lane&15), k=(lane>>4)*8
    const int a_off = (wr + (lane & 15)) * 32 + (lane >> 4) * 8;
    const int b_off = (lane & 15) * 32 + (lane >> 4) * 8;

    auto do_stage = [&](bf16* AsB, bf16* BsB, int kt) {
        const size_t kb = (size_t)kt * 2;
        char* Ad = (char*)AsB + wave * 4096;
        char* Bd = (char*)BsB + wave * 2048;
#pragma unroll
        for (int q = 0; q < 4; q++) g2l16(Ag + kb + q * rs16, Ad + q * 1024);
#pragma unroll
        for (int q = 0; q < 2; q++) g2l16(Bg + kb + q * rs16, Bd + q * 1024);
    };
    auto do_mfma = [&](const bf16* AsB, const bf16* BsB) {
        bf16x8 a[4], b[4];
#pragma unroll
        for (int mt = 0; mt < 4; mt++) a[mt] = *(const bf16x8*)(AsB + a_off + mt * 512);
#pragma unroll
        for (int nt = 0; nt < 4; nt++) b[nt] = *(const bf16x8*)(BsB + b_off + nt * 512);
#pragma unroll
        for (int mt = 0; mt < 4; mt++)
#pragma unroll
            for (int nt = 0; nt < 4; nt++)
                acc[mt][nt] = __builtin_amdgcn_mfma_f32_16x16x32_bf16(
                    a[mt], b[nt], acc[mt][nt], 0, 0, 0);
    };

    const int k_beg = (int)blockIdx.z * KS;
    const int k_end = k_beg + KS;
    // Proven 2-phase double-buffer: stage t+1 before computing t; one
    // __syncthreads per tile (drains vmcnt — structural cost accepted; the
    // occupancy of 4 independent blocks/CU provides the latency cover).
    do_stage(As[0], Bs[0], k_beg);
    __syncthreads();
    for (int k0 = k_beg; k0 < k_end; k0 += 64) {
        if (k0 + 32 < k_end) do_stage(As[1], Bs[1], k0 + 32);
        do_mfma(As[0], Bs[0]);
        __syncthreads();
        if (k0 + 64 < k_end) do_stage(As[0], Bs[0], k0 + 64);
        do_mfma(As[1], Bs[1]);
        __syncthreads();
    }

    // Epilogue. C/D layout: col = lane&15, row = (lane>>4)*4 + reg  [m89/m91]
    const int col = lane & 15;
    const int r0  = (lane >> 4) * 4;
    float* po = nullptr;
    if constexpr (EPI == 3)
        po = (float*)out + (size_t)blockIdx.z * ((size_t)M * (size_t)N);
#pragma unroll
    for (int mt = 0; mt < 4; mt++) {
#pragma unroll
        for (int nt = 0; nt < 4; nt++) {
            const int gn      = bn0 + nt * 16 + col;
            const int gm_base = bm0 + wr + mt * 16 + r0;
            if constexpr (EPI == 0) {
#pragma unroll
                for (int r = 0; r < 4; r++)
                    ((bf16*)out)[(size_t)(gm_base + r) * N + gn] = (bf16)acc[mt][nt][r];
            } else if constexpr (EPI == 3) {
#pragma unroll
                for (int r = 0; r < 4; r++)
                    po[(size_t)(gm_base + r) * N + gn] = acc[mt][nt][r];
            } else {
                // EPI == 1: element-wise ownership — direct iff gm >= gn.
#pragma unroll
                for (int r = 0; r < 4; r++) {
                    const int gm = gm_base + r;
                    if (gm >= gn) {
                        const float av = aux[(size_t)gm * N + gn];
                        const float v  = (gm == gn) ? 2.0f * av
                                                    : (acc[mt][nt][r] + 1.0f) * av;
                        ((bf16*)out)[(size_t)gm * N + gn] = (bf16)v;
                    }
                }
                // mirror (gn, gm) iff gm > gn; vector fast path when the
                // whole 4-row group is strictly below the diagonal.
                if (gm_base > gn) {
                    const size_t tb = (size_t)gn * N + gm_base;
                    const f32x4 at = *(const f32x4*)(aux + tb);
                    bf16x4 v;
#pragma unroll
                    for (int r = 0; r < 4; r++)
                        v[r] = (bf16)((acc[mt][nt][r] + 1.0f) * at[r]);
                    *(bf16x4*)((bf16*)out + tb) = v;
                } else {
#pragma unroll
                    for (int r = 0; r < 4; r++) {
                        const int gm = gm_base + r;
                        if (gm > gn) {
                            const size_t tb = (size_t)gn * N + gm;
                            ((bf16*)out)[tb] = (bf16)((acc[mt][nt][r] + 1.0f) * aux[tb]);
                        }
                    }
                }
            }
        }
    }
}

extern "C" void kernel_launch(void* const* d_in, const int* in_sizes, int n_in,
                              void* d_out, int out_size, void* d_ws, size_t ws_size,
                              hipStream_t stream) {
    const float* H_v   = (const float*)d_in[0];
    const float* H_e   = (const float*)d_in[1];
    // d_in[2] = adj_e : UNUSED by the reference
    const float* adj_v = (const float*)d_in[3];
    const float* T     = (const float*)d_in[4];
    const float* W     = (const float*)d_in[5];
    const float* p     = (const float*)d_in[6];
    const float* bias  = (const float*)d_in[7];
    float* out = (float*)d_out;

    // workspace layout (~176.7 MB)
    char* ws = (char*)d_ws;
    float* es  = (float*)(ws);                        // 32 KB
    bf16*  Ts  = (bf16*)(ws + 32768);                 // 64 MB
    bf16*  Tb  = (bf16*)(ws + 32768 + 67108864ull);   // 64 MB
    bf16*  A2  = (bf16*)(ws + 32768 + 134217728ull);  // 32 MB
    bf16*  Hvb = (bf16*)(ws + 32768 + 167772160ull);  // 4 MB
    bf16*  Wt  = (bf16*)(ws + 32768 + 171966464ull);  // 512 KB
    bf16*  HwT = (bf16*)(ws + 32768 + 172490752ull);  // 4 MB
    // split-K f32 partials (4 x 8 MB = 32 MB) alias Ts: Ts is dead once
    // gemm_bt<1> completes, and gemm_bt<3> is stream-ordered after it.
    float* part = (float*)(ws + 32768);

    // 1. e_scale = H_e @ p^T
    escale_k<<<N_EDGES / 4, 256, 0, stream>>>(H_e, p, es);
    // 2. bf16 conversions
    conv_T<<<(int)(((size_t)N_NODES * N_EDGES / 4) / 256), 256, 0, stream>>>(T, es, Ts, Tb);
    conv_bf16<<<(N_NODES * IN_V / 4) / 256, 256, 0, stream>>>(H_v, Hvb);
    transW<<<(IN_V * OUT_V) / 256, 256, 0, stream>>>(W, Wt);
    // second tuple output: H_e passthrough (independent; issue early)
    hipMemcpyAsync(out + (size_t)N_NODES * OUT_V, H_e,
                   (size_t)N_EDGES * IN_E * sizeof(float),
                   hipMemcpyDeviceToDevice, stream);
    // 3. HwT[j][i] = (H_v @ W)[i][j] = sum_k Wt[j,k]*Hvb[i,k]   (512 x 4096)
    gemm_bt<0><<<dim3(IN_V / 128, N_NODES / 64), 128, 0, stream>>>(
        Wt, Hvb, nullptr, HwT, IN_V, N_NODES, IN_V, IN_V);
    // 4. A2 = (M1 + 1) * adj_v, diag -> 2*adj_v  (4096 x 4096, K=8192)
    //    M1 symmetric -> triangular 128x64 grid: 32*33 = 1056 blocks.
    gemm_bt<1><<<dim3(32 * 33, 1, 1), 128, 0, stream>>>(
        Ts, Tb, adj_v, A2, N_NODES, N_NODES, N_EDGES, N_EDGES);
    // 5. partial[z] = A2 @ Hw slice  (4096 x 512, K=4096, split-K=4, f32)
    gemm_bt<3><<<dim3(N_NODES / 128, OUT_V / 64, 4), 128, 0, stream>>>(
        A2, HwT, nullptr, part, N_NODES, OUT_V, N_NODES, N_NODES / 4);
    // 6. out = bias + 0.5 * sum_z partial[z]
    finalize_k<<<(N_NODES * OUT_V / 4) / 256, 256, 0, stream>>>(part, bias, out);
}